// Round 12
// baseline (559.253 us; speedup 1.0000x reference)
//
#include <hip/hip_runtime.h>
#include <cstddef>
#include <cstdint>

#define NB 64
#define ND 1024
#define NO 31
#define NSTEPS 16
#define KS 31            // one P slice per opcode (k-chunk = 1024)
#define KT32 992         // total K32 steps = 31*1024/32

typedef _Float16 half8 __attribute__((ext_vector_type(8)));
typedef float floatx4 __attribute__((ext_vector_type(4)));

// ---- prep: softmax over opcode logits (W[b][t][o]) + signal -> h16 frag-order ----
// blocks 0..31: init16 (unit u = d8*64 + b holds h[b][d8*8+j]); blocks 32..35: softmax.
__global__ void prep_k(const float* __restrict__ logits, float* __restrict__ W,
                       const float* __restrict__ signal, _Float16* __restrict__ h16) {
    int bid = blockIdx.x;
    int tid = threadIdx.x;
    if (bid < 32) {
        int u = bid * 256 + tid;              // 8192 units
        int d8 = u >> 6, b = u & 63;
        const float* src = signal + (size_t)b * ND + d8 * 8;
        half8 v;
        #pragma unroll
        for (int j = 0; j < 8; ++j) v[j] = (_Float16)src[j];
        *(half8*)(h16 + (size_t)u * 8) = v;
    } else {
        int row = (bid - 32) * 256 + tid;     // row = b*16 + t, 1024 rows
        const float* x = logits + (size_t)row * NO;
        float m = -1e30f;
        for (int o = 0; o < NO; ++o) m = fmaxf(m, x[o]);
        float e[NO]; float s = 0.f;
        for (int o = 0; o < NO; ++o) { e[o] = expf(x[o] - m); s += e[o]; }
        float inv = 1.0f / s;
        float* wo = W + (size_t)row * NO;
        for (int o = 0; o < NO; ++o) wo[o] = e[o] * inv;
    }
}

// ---- kconv v2: coalesced tile transpose (unchanged, verified) ----
__global__ __launch_bounds__(256) void kconv_k(const float* __restrict__ K,
                                               _Float16* __restrict__ Ktf) {
    __shared__ float tile[32 * 256];           // 32 KB, swizzled cols
    int kt  = blockIdx.x >> 2;                 // 0..991
    int nb4 = blockIdx.x & 3;                  // 0..3 (256-col tile)
    int tid = threadIdx.x;
    int lane = tid & 63, w = tid >> 6;

    {
        const float* src = K + ((size_t)kt * 32) * ND + nb4 * 256;
        #pragma unroll
        for (int i = 0; i < 8; ++i) {
            int r = i * 4 + w;
            int x = lane * 4;
            int xs = x ^ (((r >> 3) & 1) << 4);
            float4 v = *(const float4*)(src + (size_t)r * ND + x);
            *(float4*)&tile[r * 256 + xs] = v;
        }
    }
    __syncthreads();

    int kl0 = (lane >> 4) * 8;
    int swz = ((lane >> 4) & 1) << 4;
    #pragma unroll
    for (int i = 0; i < 4; ++i) {
        int ns_local = i * 4 + w;
        int nl = ns_local * 16 + (lane & 15);
        int xsw = nl ^ swz;
        half8 v;
        #pragma unroll
        for (int j = 0; j < 8; ++j) v[j] = (_Float16)tile[(kl0 + j) * 256 + xsw];
        int ns = nb4 * 16 + ns_local;
        size_t unit = ((size_t)ns * KT32 + kt) * 64 + lane;
        *(half8*)(Ktf + unit * 8) = v;
    }
}

// ---- GEMM v6: P[o][b][n] = (h @ K_o); w applied in epilogue ----
// grid (8 n-tiles of 128, 31 opcodes) = 248 blocks, 256 thr (4 waves).
// A = shared fp16 h, staged in two pure-copy 64 KB passes (zero VALU);
// acc persists across passes. Wave = M64 x N32 over 32 K32 steps,
// depth-2 B prefetch. Epilogue scales by w[b][o], direct P store.
__global__ __launch_bounds__(256) void gemm_k(
    const _Float16* __restrict__ h16, const _Float16* __restrict__ Ktf,
    const float* __restrict__ W, float* __restrict__ P, int step)
{
    __shared__ _Float16 lds_a[64 * 512];   // 64 KiB per pass; half8-unit: p*64 + b
    int nb = blockIdx.x;                   // 0..7
    int o  = blockIdx.y;                   // 0..30
    int tid = threadIdx.x;                 // 0..255
    int l = tid & 63, w = tid >> 6;        // w 0..3
    int ml = l & 15, q = l >> 4;
    int ns0 = nb * 8 + w * 2;              // two n-subtiles of 16 per wave

    // ---- B stream pointers (opcode o's 32 K32 steps); prime depth-2 ----
    const half8* bp0 = (const half8*)Ktf + ((size_t)(ns0 + 0) * KT32 + (size_t)o * 32) * 64 + l;
    const half8* bp1 = (const half8*)Ktf + ((size_t)(ns0 + 1) * KT32 + (size_t)o * 32) * 64 + l;
    half8 c00 = bp0[0], c10 = bp1[0];
    half8 c01 = bp0[64], c11 = bp1[64];

    floatx4 acc[2][4] = {};

    #pragma unroll
    for (int p2 = 0; p2 < 2; ++p2) {
        // ---- stage A half: pure contiguous 64 KB copy of h16 (no VALU) ----
        if (p2) __syncthreads();               // pass-0 LDS reads done before overwrite
        {
            const half8* hg = (const half8*)h16 + (size_t)p2 * 4096;
            #pragma unroll
            for (int i = 0; i < 16; ++i) {
                int u = i * 256 + tid;
                *(half8*)&lds_a[(size_t)u * 8] = hg[u];
            }
        }
        __syncthreads();

        const half8* Ap = (const half8*)lds_a;
        #pragma unroll
        for (int s = 0; s < 16; ++s) {
            int gs = p2 * 16 + s;              // global K32 step 0..31
            half8 f0, f1;
            if (gs < 30) {                     // depth-2 prefetch (crosses pass boundary)
                f0 = bp0[(size_t)(gs + 2) * 64];
                f1 = bp1[(size_t)(gs + 2) * 64];
            }
            int abase = (s * 4 + q) * 64 + ml;
            half8 a0 = Ap[abase];
            half8 a1 = Ap[abase + 16];
            half8 a2 = Ap[abase + 32];
            half8 a3 = Ap[abase + 48];
            acc[0][0] = __builtin_amdgcn_mfma_f32_16x16x32_f16(a0, c00, acc[0][0], 0, 0, 0);
            acc[0][1] = __builtin_amdgcn_mfma_f32_16x16x32_f16(a1, c00, acc[0][1], 0, 0, 0);
            acc[0][2] = __builtin_amdgcn_mfma_f32_16x16x32_f16(a2, c00, acc[0][2], 0, 0, 0);
            acc[0][3] = __builtin_amdgcn_mfma_f32_16x16x32_f16(a3, c00, acc[0][3], 0, 0, 0);
            acc[1][0] = __builtin_amdgcn_mfma_f32_16x16x32_f16(a0, c10, acc[1][0], 0, 0, 0);
            acc[1][1] = __builtin_amdgcn_mfma_f32_16x16x32_f16(a1, c10, acc[1][1], 0, 0, 0);
            acc[1][2] = __builtin_amdgcn_mfma_f32_16x16x32_f16(a2, c10, acc[1][2], 0, 0, 0);
            acc[1][3] = __builtin_amdgcn_mfma_f32_16x16x32_f16(a3, c10, acc[1][3], 0, 0, 0);
            if (gs < 31) { c00 = c01; c10 = c11; }
            if (gs < 30) { c01 = f0; c11 = f1; }
        }
    }

    // ---- epilogue: scale by w[b][o]; C/D col = l&15, row = (l>>4)*4 + r ----
    float wtab[16];
    #pragma unroll
    for (int mt = 0; mt < 4; ++mt)
        #pragma unroll
        for (int r = 0; r < 4; ++r) {
            int b = mt * 16 + q * 4 + r;
            wtab[mt * 4 + r] = W[((size_t)b * NSTEPS + step) * NO + o];
        }
    float* Po = P + (size_t)o * (NB * ND);
    #pragma unroll
    for (int tt = 0; tt < 2; ++tt) {
        int n = (ns0 + tt) * 16 + ml;
        #pragma unroll
        for (int mt = 0; mt < 4; ++mt) {
            #pragma unroll
            for (int r = 0; r < 4; ++r) {
                int b = mt * 16 + q * 4 + r;
                Po[(size_t)b * ND + n] = acc[tt][mt][r] * wtab[mt * 4 + r];
            }
        }
    }
}

// ---- reduce KS=31 partials + gated update; emits h16 for next gemm ----
// 512 blocks x 256 thr. Block owns 128 contiguous outputs (same b).
// Wave-pairs: waves {0,1} sum o in [0,16), waves {2,3} sum o in [16,31).
__global__ void update_k(const float* __restrict__ hin, const float* __restrict__ P,
                         const float* __restrict__ operands, float* __restrict__ hout,
                         _Float16* __restrict__ h16n, int step)
{
    __shared__ float red[256];
    int tid = threadIdx.x;
    int w = tid >> 6, lane = tid & 63;
    int half = w >> 1;
    int j = (w & 1) * 64 + lane;              // output slot 0..127
    int g = blockIdx.x * 128 + j;
    const float* p = P + (size_t)(half * 16) * (NB * ND) + g;
    float s = 0.f;
    if (half == 0) {
        #pragma unroll
        for (int i = 0; i < 16; ++i) s += p[(size_t)i * (NB * ND)];
    } else {
        #pragma unroll
        for (int i = 0; i < 15; ++i) s += p[(size_t)i * (NB * ND)];
    }
    red[half * 128 + j] = s;
    __syncthreads();
    if (tid < 128) {
        float tot = red[tid] + red[tid + 128];
        int g2 = blockIdx.x * 128 + tid;
        int b = g2 >> 10, n = g2 & 1023;
        float gl = operands[((size_t)b * NSTEPS + step) * 4 + 3];
        float gt = 1.0f / (1.0f + expf(-gl));
        float val = gt * tot + (1.0f - gt) * hin[g2];
        hout[g2] = val;
        h16n[((size_t)(n >> 3) * 64 + b) * 8 + (n & 7)] = (_Float16)val;
    }
}

extern "C" void kernel_launch(void* const* d_in, const int* in_sizes, int n_in,
                              void* d_out, int out_size, void* d_ws, size_t ws_size,
                              hipStream_t stream)
{
    const float* logits   = (const float*)d_in[0];  // (64,16,31)
    const float* operands = (const float*)d_in[1];  // (64,16,4)
    const float* signal   = (const float*)d_in[2];  // (64,1024)
    const float* opk      = (const float*)d_in[3];  // (31,1024,1024)
    float* out = (float*)d_out;
    char* ws = (char*)d_ws;

    size_t offW   = 0;                                   // 126,976 B (+pad)
    size_t offP   = 131072;                              // 31*64*1024*4 = 7.75 MB
    size_t offH   = offP + (size_t)KS * NB * ND * 4;     // h fp32 x2 (512 KB)
    size_t offH16 = offH + 2ull * NB * ND * 4;           // h16 x2 (256 KB)
    size_t offK   = offH16 + 2ull * NB * ND * 2;         // Ktf: 62 MiB fp16

    float*    W    = (float*)(ws + offW);
    float*    P    = (float*)(ws + offP);
    float*    h0   = (float*)(ws + offH);
    float*    h1   = h0 + NB * ND;
    _Float16* h16a = (_Float16*)(ws + offH16);
    _Float16* h16b = h16a + NB * ND;
    _Float16* Ktf  = (_Float16*)(ws + offK);

    prep_k<<<dim3(36), 256, 0, stream>>>(logits, W, signal, h16a);
    kconv_k<<<dim3(3968), 256, 0, stream>>>(opk, Ktf);

    const float* hc = signal;
    float* hn = h0;
    _Float16* h16c = h16a;
    _Float16* h16n = h16b;
    for (int t = 0; t < NSTEPS; ++t) {
        gemm_k<<<dim3(8, KS), 256, 0, stream>>>(h16c, Ktf, W, P, t);
        float* dst = (t == NSTEPS - 1) ? out : hn;
        update_k<<<dim3(512), 256, 0, stream>>>(hc, P, operands, dst, h16n, t);
        hc = dst;
        hn = (hn == h0) ? h1 : h0;
        _Float16* tmp = h16c; h16c = h16n; h16n = tmp;
    }
}